// Round 1
// baseline (510.518 us; speedup 1.0000x reference)
//
#include <hip/hip_runtime.h>
#include <math.h>

// ---------------------------------------------------------------------------
// MLPAC_4_team: B=65536, P=3, OBS=48. Encoder (9 prop nets 2->32->64,
// 2 ext nets 6->32->288, opp 18->32->576, branches lrelu'd then summed into
// enc[576]) -> pi MLP 576->256->256->3, tanh. All matmul-shaped work on
// bf16 MFMA 16x16x32, fp32 accumulate. Threshold is bf16-floor (3.85e-3).
// ---------------------------------------------------------------------------

#define NEG_SLOPE 0.01f
#define BTOT 65536

// ws layout in ushort elements (all 16B aligned):
#define OFF_ENCB 0                 // swizzled {prop,ext,opp}_W2 B-frags
#define OFF_PW1  165888            // swizzled pi_W1
#define OFF_PW2  608256            // swizzled pi_W2
#define OFF_PW3  804864            // swizzled pi_W3 (N padded 3->16 with 0)
#define OFF_ENC  817152            // enc chunk buffer (bf16, A-frag order)

typedef short bf16x8 __attribute__((ext_vector_type(8)));
typedef float f32x4  __attribute__((ext_vector_type(4)));

__device__ __forceinline__ float lrelu(float x) { return x > 0.f ? x : NEG_SLOPE * x; }

__device__ __forceinline__ unsigned short f2bf(float x) {
  union { float f; unsigned int u; } c; c.f = x;
  unsigned int u = c.u;
  u = (u + 0x7fffu + ((u >> 16) & 1u)) >> 16;   // round-to-nearest-even
  return (unsigned short)u;
}

// ---------------------------------------------------------------------------
// prep: convert + swizzle weights into MFMA B-fragment order.
// B-frag layout for 16x16x32: lane l holds B[k=(l>>4)*8+j][n=(l&15)], j=0..7,
// stored contiguously -> one dwordx4 per lane.
// ---------------------------------------------------------------------------
__global__ __launch_bounds__(256) void prep_kernel(
    const float* __restrict__ propW2, const float* __restrict__ extW2,
    const float* __restrict__ oppW2,  const float* __restrict__ piW1,
    const float* __restrict__ piW2,   const float* __restrict__ piW3,
    unsigned short* __restrict__ ws16)
{
  const int idx = blockIdx.x * 256 + threadIdx.x;
  if (idx >= OFF_ENC) return;
  float v;
  if (idx < OFF_PW1) {
    // encB[p][kt<18][br<3][nt2<2][lane][j]
    const int j = idx & 7, lane = (idx >> 3) & 63;
    int t = idx >> 9;
    const int nt2 = t & 1; t >>= 1;
    const int br = t % 3;  t /= 3;
    const int kt = t % 18; const int p = t / 18;
    const int k = (lane >> 4) * 8 + j;
    const int n = kt * 32 + nt2 * 16 + (lane & 15);   // enc col 0..575
    if (br == 0)      { const int g = kt >> 1;       v = propW2[((p*9+g)*32 + k)*64  + (n - g*64)];  }
    else if (br == 1) { const int g = (kt >= 9);     v = extW2 [((p*2+g)*32 + k)*288 + (n - g*288)]; }
    else              {                              v = oppW2 [(p*32 + k)*576 + n]; }
  } else if (idx < OFF_PW2) {
    // piW1_sw[p][kt<18][nt<16][lane][j]
    const int i2 = idx - OFF_PW1;
    const int j = i2 & 7, lane = (i2 >> 3) & 63;
    int t = i2 >> 9;
    const int nt = t & 15; t >>= 4;
    const int kt = t % 18; const int p = t / 18;
    const int k = kt * 32 + (lane >> 4) * 8 + j;
    const int n = nt * 16 + (lane & 15);
    v = piW1[((size_t)p * 576 + k) * 256 + n];
  } else if (idx < OFF_PW3) {
    // piW2_sw[p][kt<8][nt<16][lane][j]
    const int i2 = idx - OFF_PW2;
    const int j = i2 & 7, lane = (i2 >> 3) & 63;
    int t = i2 >> 9;
    const int nt = t & 15; t >>= 4;
    const int kt = t & 7;  const int p = t >> 3;
    const int k = kt * 32 + (lane >> 4) * 8 + j;
    const int n = nt * 16 + (lane & 15);
    v = piW2[((size_t)p * 256 + k) * 256 + n];
  } else {
    // piW3_sw[p][kt<8][lane][j], N padded to 16 (cols >=3 are zero)
    const int i2 = idx - OFF_PW3;
    const int j = i2 & 7, lane = (i2 >> 3) & 63;
    int t = i2 >> 9;
    const int kt = t & 7; const int p = t >> 3;
    const int k = kt * 32 + (lane >> 4) * 8 + j;
    const int n = lane & 15;
    v = (n < 3) ? piW3[((size_t)p * 256 + k) * 3 + n] : 0.f;
  }
  ws16[idx] = f2bf(v);
}

// ---------------------------------------------------------------------------
// enc kernel: one block = 64 samples x one p. Phase A: layer-1 hiddens on
// VALU (fp32) -> LDS Hs[64][392] bf16 (cols: 9*32 prop | 2*32 ext | 32 opp).
// Phase B: W2 branches via MFMA (K=32 each), per-branch bias+lrelu, sum,
// transpose C->A layout via per-wave LDS scratch, store enc to ws in
// A-fragment order: enc_sw[p][m16][kt][lane][j].
// ---------------------------------------------------------------------------
__global__ __launch_bounds__(256) void enc_kernel(
    const float* __restrict__ obs,
    const float* __restrict__ propW1, const float* __restrict__ propB1,
    const float* __restrict__ propB2,
    const float* __restrict__ extW1,  const float* __restrict__ extB1,
    const float* __restrict__ extB2,
    const float* __restrict__ oppW1,  const float* __restrict__ oppB1,
    const float* __restrict__ oppB2,
    const unsigned short* __restrict__ encB,
    unsigned short* __restrict__ encOut,
    int b0, int chunkB)
{
  __shared__ __align__(16) unsigned short Hs[64 * 392];      // 50176 B
  __shared__ __align__(16) unsigned char  ureg[12544];       // obs (phase A) / scratch (phase B)
  float* obs_s = (float*)ureg;                               // [64][49]
  unsigned short* scratch = (unsigned short*)ureg;           // 4 waves x [32][40]

  const int tid = threadIdx.x;
  const int p = blockIdx.y;
  const int brow = blockIdx.x;

  // ---- load obs tile ----
  for (int idx = tid; idx < 64 * 48; idx += 256) {
    const int s = idx / 48, c = idx - s * 48;
    obs_s[s * 49 + c] = obs[(size_t)(b0 + brow * 64 + s) * 144 + p * 48 + c];
  }
  __syncthreads();

  // ---- phase A: layer-1 hiddens ----
  for (int idx = tid; idx < 64 * 384; idx += 256) {
    const int s = idx / 384, c = idx - s * 384;
    float acc;
    if (c < 288) {                       // prop net g=c/32: K=2
      const int g = c >> 5, o = c & 31;
      acc = propB1[(p * 9 + g) * 32 + o];
      const float* w = &propW1[((p * 9 + g) * 2) * 32 + o];
      acc += obs_s[s * 49 + 2 * g] * w[0];
      acc += obs_s[s * 49 + 2 * g + 1] * w[32];
    } else if (c < 352) {                // ext net g: K=6
      const int g = (c - 288) >> 5, o = (c - 288) & 31;
      acc = extB1[(p * 2 + g) * 32 + o];
      const float* w = &extW1[((p * 2 + g) * 6) * 32 + o];
      #pragma unroll
      for (int i = 0; i < 6; ++i) acc += obs_s[s * 49 + 18 + 6 * g + i] * w[i * 32];
    } else {                             // opp: K=18
      const int o = c - 352;
      acc = oppB1[p * 32 + o];
      const float* w = &oppW1[(p * 18) * 32 + o];
      #pragma unroll
      for (int i = 0; i < 18; ++i) acc += obs_s[s * 49 + 30 + i] * w[i * 32];
    }
    Hs[s * 392 + c] = f2bf(lrelu(acc));
  }
  __syncthreads();

  // ---- phase B ----
  const int wv = tid >> 6, l = tid & 63;
  const int lm = l & 15, q = l >> 4;
  unsigned short* sw = scratch + wv * (32 * 40);
  const int m16cnt = chunkB >> 4;

  for (int kt = wv; kt < 18; kt += 4) {
    const int gp = kt >> 1;
    const int ge = (kt >= 9);
    bf16x8 ap[4], ae[4], ao[4];
    #pragma unroll
    for (int ms = 0; ms < 4; ++ms) {
      const int row = ms * 16 + lm;
      ap[ms] = *(const bf16x8*)&Hs[row * 392 + gp * 32 + q * 8];
      ae[ms] = *(const bf16x8*)&Hs[row * 392 + 288 + ge * 32 + q * 8];
      ao[ms] = *(const bf16x8*)&Hs[row * 392 + 352 + q * 8];
    }
    float bp[2], be[2], bo[2];
    bf16x8 wp[2], we[2], wo[2];
    #pragma unroll
    for (int nt2 = 0; nt2 < 2; ++nt2) {
      const int n = kt * 32 + nt2 * 16 + lm;
      bp[nt2] = propB2[(p * 9 + gp) * 64 + (n - gp * 64)];
      be[nt2] = extB2[(p * 2 + ge) * 288 + (n - ge * 288)];
      bo[nt2] = oppB2[p * 576 + n];
      wp[nt2] = *(const bf16x8*)&encB[(size_t)(((((p * 18 + kt) * 3 + 0) * 2 + nt2) * 64) + l) * 8];
      we[nt2] = *(const bf16x8*)&encB[(size_t)(((((p * 18 + kt) * 3 + 1) * 2 + nt2) * 64) + l) * 8];
      wo[nt2] = *(const bf16x8*)&encB[(size_t)(((((p * 18 + kt) * 3 + 2) * 2 + nt2) * 64) + l) * 8];
    }
    #pragma unroll
    for (int half = 0; half < 2; ++half) {
      #pragma unroll
      for (int msl = 0; msl < 2; ++msl) {
        const int ms = half * 2 + msl;
        #pragma unroll
        for (int nt2 = 0; nt2 < 2; ++nt2) {
          f32x4 zz = {0.f, 0.f, 0.f, 0.f};
          f32x4 accp = __builtin_amdgcn_mfma_f32_16x16x32_bf16(ap[ms], wp[nt2], zz, 0, 0, 0);
          f32x4 acce = __builtin_amdgcn_mfma_f32_16x16x32_bf16(ae[ms], we[nt2], zz, 0, 0, 0);
          f32x4 acco = __builtin_amdgcn_mfma_f32_16x16x32_bf16(ao[ms], wo[nt2], zz, 0, 0, 0);
          #pragma unroll
          for (int r = 0; r < 4; ++r) {
            const float v = lrelu(accp[r] + bp[nt2]) + lrelu(acce[r] + be[nt2]) + lrelu(acco[r] + bo[nt2]);
            sw[(msl * 16 + q * 4 + r) * 40 + nt2 * 16 + lm] = f2bf(v);   // C-layout write
          }
        }
      }
      __asm__ volatile("s_waitcnt lgkmcnt(0)" ::: "memory");
      #pragma unroll
      for (int msl = 0; msl < 2; ++msl) {
        const int ms = half * 2 + msl;
        bf16x8 fr = *(const bf16x8*)&sw[(msl * 16 + lm) * 40 + q * 8];   // A-layout read
        *(bf16x8*)&encOut[(((((size_t)p * m16cnt + brow * 4 + ms) * 18) + kt) * 64 + l) * 8] = fr;
      }
      __asm__ volatile("s_waitcnt lgkmcnt(0)" ::: "memory");
    }
  }
}

// ---------------------------------------------------------------------------
// pi kernel: one block = 64 samples x one p; 4 waves split N=256 into 64-col
// strips. A-frags come straight from the pre-swizzled enc in ws (L2-hot);
// h1/h2 round-trip through one LDS buffer; 256->3 layer via MFMA (N padded).
// ---------------------------------------------------------------------------
__global__ __launch_bounds__(256) void pi_kernel(
    const unsigned short* __restrict__ encIn,
    const unsigned short* __restrict__ w1sw,
    const unsigned short* __restrict__ w2sw,
    const unsigned short* __restrict__ w3sw,
    const float* __restrict__ b1v, const float* __restrict__ b2v,
    const float* __restrict__ b3v,
    float* __restrict__ out, int b0, int chunkB)
{
  __shared__ __align__(16) unsigned short h1s[64 * 264];   // 33792 B
  const int tid = threadIdx.x;
  const int p = blockIdx.y, brow = blockIdx.x;
  const int wv = tid >> 6, l = tid & 63, lm = l & 15, q = l >> 4;
  const size_t plane = (size_t)p * ((size_t)chunkB * 576);

  f32x4 acc[4][4];
  {
    f32x4 zz = {0.f, 0.f, 0.f, 0.f};
    #pragma unroll
    for (int a = 0; a < 4; ++a)
      #pragma unroll
      for (int b = 0; b < 4; ++b) acc[a][b] = zz;
  }

  // ---- layer 1: 576 -> 256 ----
  for (int kt = 0; kt < 18; ++kt) {
    bf16x8 afr[4], bfr[4];
    #pragma unroll
    for (int ms = 0; ms < 4; ++ms)
      afr[ms] = *(const bf16x8*)&encIn[plane + (((size_t)(brow * 4 + ms) * 18 + kt) * 64 + l) * 8];
    #pragma unroll
    for (int nt = 0; nt < 4; ++nt)
      bfr[nt] = *(const bf16x8*)&w1sw[(size_t)((((p * 18 + kt) * 16) + wv * 4 + nt) * 64 + l) * 8];
    #pragma unroll
    for (int ms = 0; ms < 4; ++ms)
      #pragma unroll
      for (int nt = 0; nt < 4; ++nt)
        acc[ms][nt] = __builtin_amdgcn_mfma_f32_16x16x32_bf16(afr[ms], bfr[nt], acc[ms][nt], 0, 0, 0);
  }
  #pragma unroll
  for (int ms = 0; ms < 4; ++ms)
    #pragma unroll
    for (int nt = 0; nt < 4; ++nt) {
      const int n = wv * 64 + nt * 16 + lm;
      const float bias = b1v[p * 256 + n];
      #pragma unroll
      for (int r = 0; r < 4; ++r)
        h1s[(ms * 16 + q * 4 + r) * 264 + n] = f2bf(lrelu(acc[ms][nt][r] + bias));
    }
  __syncthreads();

  // ---- layer 2: 256 -> 256 ----
  {
    f32x4 zz = {0.f, 0.f, 0.f, 0.f};
    #pragma unroll
    for (int a = 0; a < 4; ++a)
      #pragma unroll
      for (int b = 0; b < 4; ++b) acc[a][b] = zz;
  }
  for (int kt = 0; kt < 8; ++kt) {
    bf16x8 afr[4], bfr[4];
    #pragma unroll
    for (int ms = 0; ms < 4; ++ms)
      afr[ms] = *(const bf16x8*)&h1s[(ms * 16 + lm) * 264 + kt * 32 + q * 8];
    #pragma unroll
    for (int nt = 0; nt < 4; ++nt)
      bfr[nt] = *(const bf16x8*)&w2sw[(size_t)((((p * 8 + kt) * 16) + wv * 4 + nt) * 64 + l) * 8];
    #pragma unroll
    for (int ms = 0; ms < 4; ++ms)
      #pragma unroll
      for (int nt = 0; nt < 4; ++nt)
        acc[ms][nt] = __builtin_amdgcn_mfma_f32_16x16x32_bf16(afr[ms], bfr[nt], acc[ms][nt], 0, 0, 0);
  }
  #pragma unroll
  for (int ms = 0; ms < 4; ++ms)
    #pragma unroll
    for (int nt = 0; nt < 4; ++nt) {
      const int n = wv * 64 + nt * 16 + lm;
      const float bias = b2v[p * 256 + n];
      #pragma unroll
      for (int r = 0; r < 4; ++r)
        acc[ms][nt][r] = lrelu(acc[ms][nt][r] + bias);
    }
  __syncthreads();            // all h1 reads complete before overwrite
  #pragma unroll
  for (int ms = 0; ms < 4; ++ms)
    #pragma unroll
    for (int nt = 0; nt < 4; ++nt) {
      const int n = wv * 64 + nt * 16 + lm;
      #pragma unroll
      for (int r = 0; r < 4; ++r)
        h1s[(ms * 16 + q * 4 + r) * 264 + n] = f2bf(acc[ms][nt][r]);   // h2
    }
  __syncthreads();

  // ---- layer 3: 256 -> 3 (N padded to 16), wave wv owns rows wv*16..+15 ----
  f32x4 a3 = {0.f, 0.f, 0.f, 0.f};
  for (int kt = 0; kt < 8; ++kt) {
    bf16x8 afr = *(const bf16x8*)&h1s[(wv * 16 + lm) * 264 + kt * 32 + q * 8];
    bf16x8 bfr = *(const bf16x8*)&w3sw[(size_t)((p * 8 + kt) * 64 + l) * 8];
    a3 = __builtin_amdgcn_mfma_f32_16x16x32_bf16(afr, bfr, a3, 0, 0, 0);
  }
  if (lm < 3) {
    const float bias3 = b3v[p * 3 + lm];
    #pragma unroll
    for (int r = 0; r < 4; ++r) {
      const int s = wv * 16 + q * 4 + r;
      out[(size_t)(b0 + brow * 64 + s) * 9 + p * 3 + lm] = tanhf(a3[r] + bias3);
    }
  }
}

// ---------------------------------------------------------------------------
extern "C" void kernel_launch(void* const* d_in, const int* in_sizes, int n_in,
                              void* d_out, int out_size, void* d_ws, size_t ws_size,
                              hipStream_t stream)
{
  const float* obs    = (const float*)d_in[0];
  const float* propW1 = (const float*)d_in[1];
  const float* propB1 = (const float*)d_in[2];
  const float* propW2 = (const float*)d_in[3];
  const float* propB2 = (const float*)d_in[4];
  const float* extW1  = (const float*)d_in[5];
  const float* extB1  = (const float*)d_in[6];
  const float* extW2  = (const float*)d_in[7];
  const float* extB2  = (const float*)d_in[8];
  const float* oppW1  = (const float*)d_in[9];
  const float* oppB1  = (const float*)d_in[10];
  const float* oppW2  = (const float*)d_in[11];
  const float* oppB2  = (const float*)d_in[12];
  const float* piW1   = (const float*)d_in[13];
  const float* piB1   = (const float*)d_in[14];
  const float* piW2   = (const float*)d_in[15];
  const float* piB2   = (const float*)d_in[16];
  const float* piW3   = (const float*)d_in[17];
  const float* piB3   = (const float*)d_in[18];
  float* out = (float*)d_out;
  unsigned short* ws16 = (unsigned short*)d_ws;

  // pick largest chunk (fewest launches) whose enc buffer fits ws
  const size_t fixedBytes = (size_t)OFF_ENC * 2;
  int chunks = 1;
  while (chunks < 64) {
    const size_t encBytes = ((size_t)BTOT / chunks) * 3 * 576 * 2;
    if (fixedBytes + encBytes <= ws_size) break;
    chunks <<= 1;
  }
  const int chunkB = BTOT / chunks;
  unsigned short* encW = ws16 + OFF_ENC;

  prep_kernel<<<dim3((OFF_ENC + 255) / 256), dim3(256), 0, stream>>>(
      propW2, extW2, oppW2, piW1, piW2, piW3, ws16);

  for (int c = 0; c < chunks; ++c) {
    const int b0 = c * chunkB;
    enc_kernel<<<dim3(chunkB / 64, 3), dim3(256), 0, stream>>>(
        obs, propW1, propB1, propB2, extW1, extB1, extB2,
        oppW1, oppB1, oppB2, ws16 + OFF_ENCB, encW, b0, chunkB);
    pi_kernel<<<dim3(chunkB / 64, 3), dim3(256), 0, stream>>>(
        encW, ws16 + OFF_PW1, ws16 + OFF_PW2, ws16 + OFF_PW3,
        piB1, piB2, piB3, out, b0, chunkB);
  }
}

// Round 2
// 329.067 us; speedup vs baseline: 1.5514x; 1.5514x over previous
//
#include <hip/hip_runtime.h>
#include <math.h>

// ---------------------------------------------------------------------------
// MLPAC_4_team fused: B=65536, P=3. One fused kernel per (64-sample, p) block:
//   phase 0: obs -> LDS (bf16)
//   phase 1: layer-1 hiddens on the fly in A-frag regs -> 3-branch W2 MFMAs
//            -> bias/lrelu/sum -> enc in LDS (natural layout, padded)
//   phase 2: pi L1 576->256 (A-frags straight from enc LDS)
//   phase 3: pi L2 256->256 (h1 reuses enc LDS buffer)
//   phase 4: pi L3 256->3 (N padded to 16) + tanh -> out
// Weights pre-swizzled to B-frag layout each launch by prep_kernel (ws).
// ---------------------------------------------------------------------------

#define NEG_SLOPE 0.01f

// ws layout in ushort elements:
#define OFF_ENCB 0                 // {prop,ext,opp}_W2 B-frags
#define OFF_PW1  165888
#define OFF_PW2  608256
#define OFF_PW3  804864
#define WS_TOTAL 817152

#define ENC_STRIDE 584             // shorts per enc row (576 + 8 pad, 16B-mult)
#define H_STRIDE   264             // shorts per h1/h2 row

typedef short bf16x8 __attribute__((ext_vector_type(8)));
typedef float f32x4  __attribute__((ext_vector_type(4)));

__device__ __forceinline__ float lrelu(float x) { return x > 0.f ? x : NEG_SLOPE * x; }

__device__ __forceinline__ unsigned short f2bf(float x) {
  union { float f; unsigned int u; } c; c.f = x;
  unsigned int u = (c.u + 0x7fffu + ((c.u >> 16) & 1u)) >> 16;  // RNE
  return (unsigned short)u;
}
__device__ __forceinline__ float bf2f(unsigned short h) {
  union { unsigned int u; float f; } c; c.u = ((unsigned int)h) << 16;
  return c.f;
}

// ---------------------------------------------------------------------------
// prep: swizzle weights into MFMA B-frag order (lane l holds B[k=(l>>4)*8+j][n=l&15]).
// ---------------------------------------------------------------------------
__global__ __launch_bounds__(256) void prep_kernel(
    const float* __restrict__ propW2, const float* __restrict__ extW2,
    const float* __restrict__ oppW2,  const float* __restrict__ piW1,
    const float* __restrict__ piW2,   const float* __restrict__ piW3,
    unsigned short* __restrict__ ws16)
{
  const int idx = blockIdx.x * 256 + threadIdx.x;
  if (idx >= WS_TOTAL) return;
  float v;
  if (idx < OFF_PW1) {
    // encB[p][kt<18][br<3][nt2<2][lane][j]
    const int j = idx & 7, lane = (idx >> 3) & 63;
    int t = idx >> 9;
    const int nt2 = t & 1; t >>= 1;
    const int br = t % 3;  t /= 3;
    const int kt = t % 18; const int p = t / 18;
    const int k = (lane >> 4) * 8 + j;
    const int n = kt * 32 + nt2 * 16 + (lane & 15);
    if (br == 0)      { const int g = kt >> 1;   v = propW2[((p*9+g)*32 + k)*64  + (n - g*64)];  }
    else if (br == 1) { const int g = (kt >= 9); v = extW2 [((p*2+g)*32 + k)*288 + (n - g*288)]; }
    else              {                          v = oppW2 [(p*32 + k)*576 + n]; }
  } else if (idx < OFF_PW2) {
    const int i2 = idx - OFF_PW1;
    const int j = i2 & 7, lane = (i2 >> 3) & 63;
    int t = i2 >> 9;
    const int nt = t & 15; t >>= 4;
    const int kt = t % 18; const int p = t / 18;
    const int k = kt * 32 + (lane >> 4) * 8 + j;
    const int n = nt * 16 + (lane & 15);
    v = piW1[(p * 576 + k) * 256 + n];
  } else if (idx < OFF_PW3) {
    const int i2 = idx - OFF_PW2;
    const int j = i2 & 7, lane = (i2 >> 3) & 63;
    int t = i2 >> 9;
    const int nt = t & 15; t >>= 4;
    const int kt = t & 7;  const int p = t >> 3;
    const int k = kt * 32 + (lane >> 4) * 8 + j;
    const int n = nt * 16 + (lane & 15);
    v = piW2[(p * 256 + k) * 256 + n];
  } else {
    const int i2 = idx - OFF_PW3;
    const int j = i2 & 7, lane = (i2 >> 3) & 63;
    int t = i2 >> 9;
    const int kt = t & 7; const int p = t >> 3;
    const int k = kt * 32 + (lane >> 4) * 8 + j;
    const int n = lane & 15;
    v = (n < 3) ? piW3[(p * 256 + k) * 3 + n] : 0.f;
  }
  ws16[idx] = f2bf(v);
}

// ---------------------------------------------------------------------------
__global__ __launch_bounds__(256, 2) void fused_kernel(
    const float* __restrict__ obs,
    const float* __restrict__ propW1, const float* __restrict__ propB1,
    const float* __restrict__ propB2,
    const float* __restrict__ extW1,  const float* __restrict__ extB1,
    const float* __restrict__ extB2,
    const float* __restrict__ oppW1,  const float* __restrict__ oppB1,
    const float* __restrict__ oppB2,
    const unsigned short* __restrict__ encB,
    const unsigned short* __restrict__ w1sw,
    const unsigned short* __restrict__ w2sw,
    const unsigned short* __restrict__ w3sw,
    const float* __restrict__ b1v, const float* __restrict__ b2v,
    const float* __restrict__ b3v,
    float* __restrict__ out)
{
  __shared__ __align__(16) unsigned short obs_s[64 * 52];        // 6656 B
  __shared__ __align__(16) unsigned short enc_s[64 * ENC_STRIDE];// 74752 B  (total 81408 -> 2 blk/CU)

  const int tid = threadIdx.x;
  const int p = blockIdx.y, brow = blockIdx.x;
  const int sbase = brow * 64;

  // ---- phase 0: obs tile -> LDS bf16 ----
  {
    const int s = tid >> 2, c0 = (tid & 3) * 12;
    const float* src = &obs[(sbase + s) * 144 + p * 48 + c0];
    float4 v0 = *(const float4*)(src);
    float4 v1 = *(const float4*)(src + 4);
    float4 v2 = *(const float4*)(src + 8);
    unsigned short* dst = &obs_s[s * 52 + c0];
    dst[0] = f2bf(v0.x); dst[1] = f2bf(v0.y); dst[2]  = f2bf(v0.z); dst[3]  = f2bf(v0.w);
    dst[4] = f2bf(v1.x); dst[5] = f2bf(v1.y); dst[6]  = f2bf(v1.z); dst[7]  = f2bf(v1.w);
    dst[8] = f2bf(v2.x); dst[9] = f2bf(v2.y); dst[10] = f2bf(v2.z); dst[11] = f2bf(v2.w);
  }
  __syncthreads();

  const int wv = tid >> 6, l = tid & 63, lm = l & 15, q = l >> 4;

  // ---- phase 1: enc -> LDS ----
  {
    // opp A-frags (kt-independent): lane holds H_opp[ms*16+lm][q*8+j]
    bf16x8 ao[4];
    {
      float xo[4][18];
      #pragma unroll
      for (int ms = 0; ms < 4; ++ms)
        #pragma unroll
        for (int i = 0; i < 18; ++i)
          xo[ms][i] = bf2f(obs_s[(ms * 16 + lm) * 52 + 30 + i]);
      #pragma unroll
      for (int j = 0; j < 8; ++j) {
        const int o = q * 8 + j;
        const float bb = oppB1[p * 32 + o];
        float w[18];
        #pragma unroll
        for (int i = 0; i < 18; ++i) w[i] = oppW1[(p * 18 + i) * 32 + o];
        #pragma unroll
        for (int ms = 0; ms < 4; ++ms) {
          float h = bb;
          #pragma unroll
          for (int i = 0; i < 18; ++i) h += xo[ms][i] * w[i];
          ao[ms][j] = (short)f2bf(lrelu(h));
        }
      }
    }

    auto ext_frags = [&](int ge, bf16x8* ae) {
      float xe[4][6];
      #pragma unroll
      for (int ms = 0; ms < 4; ++ms)
        #pragma unroll
        for (int i = 0; i < 6; ++i)
          xe[ms][i] = bf2f(obs_s[(ms * 16 + lm) * 52 + 18 + 6 * ge + i]);
      #pragma unroll
      for (int j = 0; j < 8; ++j) {
        const int o = q * 8 + j;
        const float bb = extB1[(p * 2 + ge) * 32 + o];
        float w[6];
        #pragma unroll
        for (int i = 0; i < 6; ++i) w[i] = extW1[((p * 2 + ge) * 6 + i) * 32 + o];
        #pragma unroll
        for (int ms = 0; ms < 4; ++ms) {
          float h = bb;
          #pragma unroll
          for (int i = 0; i < 6; ++i) h += xe[ms][i] * w[i];
          ae[ms][j] = (short)f2bf(lrelu(h));
        }
      }
    };

    bf16x8 ae[4];
    ext_frags(0, ae);
    int cur_ge = 0;

    for (int kt = wv; kt < 18; kt += 4) {
      const int ge = (kt >= 9);
      if (ge != cur_ge) { ext_frags(1, ae); cur_ge = 1; }  // wave-uniform, once
      const int gp = kt >> 1;

      // prop A-frags on the fly (K=2)
      bf16x8 apf[4];
      {
        float w0[8], w1[8], bb[8];
        #pragma unroll
        for (int j = 0; j < 8; ++j) {
          const int o = q * 8 + j;
          w0[j] = propW1[((p * 9 + gp) * 2 + 0) * 32 + o];
          w1[j] = propW1[((p * 9 + gp) * 2 + 1) * 32 + o];
          bb[j] = propB1[(p * 9 + gp) * 32 + o];
        }
        #pragma unroll
        for (int ms = 0; ms < 4; ++ms) {
          const int row = ms * 16 + lm;
          const float x0 = bf2f(obs_s[row * 52 + 2 * gp]);
          const float x1 = bf2f(obs_s[row * 52 + 2 * gp + 1]);
          #pragma unroll
          for (int j = 0; j < 8; ++j)
            apf[ms][j] = (short)f2bf(lrelu(bb[j] + x0 * w0[j] + x1 * w1[j]));
        }
      }

      // B-frags + branch biases
      const int ebase = (p * 18 + kt) * 6;
      bf16x8 wpf[2], wef[2], wof[2];
      float bp[2], be2[2], bo2[2];
      #pragma unroll
      for (int nt2 = 0; nt2 < 2; ++nt2) {
        wpf[nt2] = *(const bf16x8*)&encB[((ebase + 0 + nt2) * 64 + l) * 8];
        wef[nt2] = *(const bf16x8*)&encB[((ebase + 2 + nt2) * 64 + l) * 8];
        wof[nt2] = *(const bf16x8*)&encB[((ebase + 4 + nt2) * 64 + l) * 8];
        const int ncol = kt * 32 + nt2 * 16 + lm;
        bp[nt2] = propB2[(p * 9 + gp) * 64 + ((kt & 1) * 32 + nt2 * 16 + lm)];
        be2[nt2] = extB2[(p * 2 + ge) * 288 + (ncol - ge * 288)];
        bo2[nt2] = oppB2[p * 576 + ncol];
      }

      #pragma unroll
      for (int ms = 0; ms < 4; ++ms) {
        #pragma unroll
        for (int nt2 = 0; nt2 < 2; ++nt2) {
          const f32x4 zz = {0.f, 0.f, 0.f, 0.f};
          f32x4 cp = __builtin_amdgcn_mfma_f32_16x16x32_bf16(apf[ms], wpf[nt2], zz, 0, 0, 0);
          f32x4 ce = __builtin_amdgcn_mfma_f32_16x16x32_bf16(ae[ms],  wef[nt2], zz, 0, 0, 0);
          f32x4 co = __builtin_amdgcn_mfma_f32_16x16x32_bf16(ao[ms],  wof[nt2], zz, 0, 0, 0);
          #pragma unroll
          for (int r = 0; r < 4; ++r) {
            const float v = lrelu(cp[r] + bp[nt2]) + lrelu(ce[r] + be2[nt2]) + lrelu(co[r] + bo2[nt2]);
            enc_s[(ms * 16 + q * 4 + r) * ENC_STRIDE + kt * 32 + nt2 * 16 + lm] = f2bf(v);
          }
        }
      }
    }
  }
  __syncthreads();

  // ---- phase 2: pi layer 1 (576 -> 256) ----
  f32x4 acc[4][4];
  {
    const f32x4 zz = {0.f, 0.f, 0.f, 0.f};
    #pragma unroll
    for (int a = 0; a < 4; ++a)
      #pragma unroll
      for (int b = 0; b < 4; ++b) acc[a][b] = zz;
  }
  for (int kt = 0; kt < 18; ++kt) {
    bf16x8 afr[4], bfr[4];
    #pragma unroll
    for (int ms = 0; ms < 4; ++ms)
      afr[ms] = *(const bf16x8*)&enc_s[(ms * 16 + lm) * ENC_STRIDE + kt * 32 + q * 8];
    const int wb = ((p * 18 + kt) * 16 + wv * 4) * 512 + l * 8;
    #pragma unroll
    for (int nt = 0; nt < 4; ++nt)
      bfr[nt] = *(const bf16x8*)&w1sw[wb + nt * 512];
    #pragma unroll
    for (int ms = 0; ms < 4; ++ms)
      #pragma unroll
      for (int nt = 0; nt < 4; ++nt)
        acc[ms][nt] = __builtin_amdgcn_mfma_f32_16x16x32_bf16(afr[ms], bfr[nt], acc[ms][nt], 0, 0, 0);
  }
  __syncthreads();                       // all enc reads done
  #pragma unroll
  for (int ms = 0; ms < 4; ++ms)
    #pragma unroll
    for (int nt = 0; nt < 4; ++nt) {
      const int n = wv * 64 + nt * 16 + lm;
      const float bias = b1v[p * 256 + n];
      #pragma unroll
      for (int r = 0; r < 4; ++r)
        enc_s[(ms * 16 + q * 4 + r) * H_STRIDE + n] = f2bf(lrelu(acc[ms][nt][r] + bias));
    }
  __syncthreads();

  // ---- phase 3: pi layer 2 (256 -> 256) ----
  {
    const f32x4 zz = {0.f, 0.f, 0.f, 0.f};
    #pragma unroll
    for (int a = 0; a < 4; ++a)
      #pragma unroll
      for (int b = 0; b < 4; ++b) acc[a][b] = zz;
  }
  for (int kt = 0; kt < 8; ++kt) {
    bf16x8 afr[4], bfr[4];
    #pragma unroll
    for (int ms = 0; ms < 4; ++ms)
      afr[ms] = *(const bf16x8*)&enc_s[(ms * 16 + lm) * H_STRIDE + kt * 32 + q * 8];
    const int wb = ((p * 8 + kt) * 16 + wv * 4) * 512 + l * 8;
    #pragma unroll
    for (int nt = 0; nt < 4; ++nt)
      bfr[nt] = *(const bf16x8*)&w2sw[wb + nt * 512];
    #pragma unroll
    for (int ms = 0; ms < 4; ++ms)
      #pragma unroll
      for (int nt = 0; nt < 4; ++nt)
        acc[ms][nt] = __builtin_amdgcn_mfma_f32_16x16x32_bf16(afr[ms], bfr[nt], acc[ms][nt], 0, 0, 0);
  }
  #pragma unroll
  for (int ms = 0; ms < 4; ++ms)
    #pragma unroll
    for (int nt = 0; nt < 4; ++nt) {
      const int n = wv * 64 + nt * 16 + lm;
      const float bias = b2v[p * 256 + n];
      #pragma unroll
      for (int r = 0; r < 4; ++r)
        acc[ms][nt][r] = lrelu(acc[ms][nt][r] + bias);
    }
  __syncthreads();                       // all h1 reads done
  #pragma unroll
  for (int ms = 0; ms < 4; ++ms)
    #pragma unroll
    for (int nt = 0; nt < 4; ++nt) {
      const int n = wv * 64 + nt * 16 + lm;
      #pragma unroll
      for (int r = 0; r < 4; ++r)
        enc_s[(ms * 16 + q * 4 + r) * H_STRIDE + n] = f2bf(acc[ms][nt][r]);  // h2
    }
  __syncthreads();

  // ---- phase 4: pi layer 3 (256 -> 3, N padded to 16) ----
  f32x4 a3 = {0.f, 0.f, 0.f, 0.f};
  for (int kt = 0; kt < 8; ++kt) {
    bf16x8 afr = *(const bf16x8*)&enc_s[(wv * 16 + lm) * H_STRIDE + kt * 32 + q * 8];
    bf16x8 bfr = *(const bf16x8*)&w3sw[(p * 8 + kt) * 512 + l * 8];
    a3 = __builtin_amdgcn_mfma_f32_16x16x32_bf16(afr, bfr, a3, 0, 0, 0);
  }
  if (lm < 3) {
    const float bias3 = b3v[p * 3 + lm];
    #pragma unroll
    for (int r = 0; r < 4; ++r) {
      const int s = wv * 16 + q * 4 + r;
      out[(sbase + s) * 9 + p * 3 + lm] = tanhf(a3[r] + bias3);
    }
  }
}

// ---------------------------------------------------------------------------
extern "C" void kernel_launch(void* const* d_in, const int* in_sizes, int n_in,
                              void* d_out, int out_size, void* d_ws, size_t ws_size,
                              hipStream_t stream)
{
  const float* obs    = (const float*)d_in[0];
  const float* propW1 = (const float*)d_in[1];
  const float* propB1 = (const float*)d_in[2];
  const float* propW2 = (const float*)d_in[3];
  const float* propB2 = (const float*)d_in[4];
  const float* extW1  = (const float*)d_in[5];
  const float* extB1  = (const float*)d_in[6];
  const float* extW2  = (const float*)d_in[7];
  const float* extB2  = (const float*)d_in[8];
  const float* oppW1  = (const float*)d_in[9];
  const float* oppB1  = (const float*)d_in[10];
  const float* oppW2  = (const float*)d_in[11];
  const float* oppB2  = (const float*)d_in[12];
  const float* piW1   = (const float*)d_in[13];
  const float* piB1   = (const float*)d_in[14];
  const float* piW2   = (const float*)d_in[15];
  const float* piB2   = (const float*)d_in[16];
  const float* piW3   = (const float*)d_in[17];
  const float* piB3   = (const float*)d_in[18];
  float* out = (float*)d_out;
  unsigned short* ws16 = (unsigned short*)d_ws;

  prep_kernel<<<dim3((WS_TOTAL + 255) / 256), dim3(256), 0, stream>>>(
      propW2, extW2, oppW2, piW1, piW2, piW3, ws16);

  fused_kernel<<<dim3(65536 / 64, 3), dim3(256), 0, stream>>>(
      obs, propW1, propB1, propB2, extW1, extB1, extB2,
      oppW1, oppB1, oppB2,
      ws16 + OFF_ENCB, ws16 + OFF_PW1, ws16 + OFF_PW2, ws16 + OFF_PW3,
      piB1, piB2, piB3, out);
}

// Round 3
// 307.338 us; speedup vs baseline: 1.6611x; 1.0707x over previous
//
#include <hip/hip_runtime.h>
#include <math.h>

// ---------------------------------------------------------------------------
// MLPAC_4_team fused v3: B=65536, P=3.
// prep: build bf16 B-fragment weight images in ws (incl. block-diag ext+opp
//       layer-1 "B1a", and k-position-permuted W2/pi weights so epilogues can
//       pair-pack with v_perm_b32).
// fused (per 64-sample x p block, 256 thr, 3 blocks/CU):
//   ph0 : obs -> LDS bf16 [64][56]
//   ph1a: ext+opp layer-1 via MFMA (K=32 window obs[16..48)) -> Hs LDS
//   loop g=0..2 (enc ping-pong, 6 k-tiles each):
//     1b : prop layer-1 on VALU (K=2) + 3-branch W2 MFMAs + lrelu-sum
//          -> enc group in LDS (pair-packed)
//     L1 : partial pi layer-1 accumulation over this group's 6 k-tiles
//   h1 -> LDS (reuses enc region); L2 256->256; h2 -> LDS; L3 256->3 + tanh.
// ---------------------------------------------------------------------------

#define NEG_SLOPE 0.01f

// ws offsets in ushort elements
#define OFF_B1A  0
#define OFF_ENCB 9216
#define OFF_PW1  175104
#define OFF_PW2  617472
#define OFF_PW3  814080
#define WS_TOTAL 826368

#define OBS_STRIDE 56     // shorts/row (48 used)
#define HS_STRIDE  104    // shorts/row (96 used: ext0|ext1|opp)
#define ENC_STRIDE 200    // shorts/row (6*32 used)
#define H_STRIDE   264    // shorts/row (256 used)

typedef short bf16x8 __attribute__((ext_vector_type(8)));
typedef float f32x4  __attribute__((ext_vector_type(4)));

__device__ __forceinline__ float lrelu(float x) { return fmaxf(x, NEG_SLOPE * x); }

__device__ __forceinline__ float u2f(unsigned int u) {
  union { unsigned int u; float f; } c; c.u = u; return c.f;
}

// pack two f32 -> two bf16 (round-half-up) in one v_perm_b32
__device__ __forceinline__ unsigned int pk2bf(float a, float b) {
  union { float f; unsigned int u; } ca, cb; ca.f = a; cb.f = b;
  return __builtin_amdgcn_perm(cb.u + 0x8000u, ca.u + 0x8000u, 0x07060302u);
}

__device__ __forceinline__ unsigned short f2bf(float x) {  // RNE, prep only
  union { float f; unsigned int u; } c; c.f = x;
  unsigned int u = (c.u + 0x7fffu + ((c.u >> 16) & 1u)) >> 16;
  return (unsigned short)u;
}

// ---------------------------------------------------------------------------
// prep: B-frag layout: lane l holds B[k_pos=(l>>4)*8+j][n=l&15], j=0..7.
// Pair-packed activations store col n at position p: n(p) = (p&1)*16 + (p>>1)
// within each 32-wide k-group -> weight rows indexed by kperm. Prop H and obs
// are in natural order (no perm).
// ---------------------------------------------------------------------------
__global__ __launch_bounds__(256) void prep_kernel(
    const float* __restrict__ propW2, const float* __restrict__ extW1,
    const float* __restrict__ extW2,  const float* __restrict__ oppW1,
    const float* __restrict__ oppW2,  const float* __restrict__ piW1,
    const float* __restrict__ piW2,   const float* __restrict__ piW3,
    unsigned short* __restrict__ ws16)
{
  const int idx = blockIdx.x * 256 + threadIdx.x;
  if (idx >= WS_TOTAL) return;
  const int j = idx & 7, lane = (idx >> 3) & 63;
  const int lm = lane & 15;
  const int k_pos = ((lane >> 4) << 3) + j;
  const int kperm = (k_pos & 1) * 16 + (k_pos >> 1);
  float v;
  if (idx < OFF_ENCB) {
    // B1a[p][go*2+nt2][lane][j]: rows = obs dims 16..47 (natural), cols 0..95
    int t = idx >> 9;
    const int nt2 = t & 1; t >>= 1;
    const int go = t % 3; const int p = t / 3;
    const int d = 16 + k_pos;
    const int n = go * 32 + nt2 * 16 + lm;
    if (n < 64) {
      const int g = n >> 5, o = n & 31, i = d - 18 - 6 * g;
      v = (i >= 0 && i < 6) ? extW1[((p * 2 + g) * 6 + i) * 32 + o] : 0.f;
    } else {
      const int o = n - 64, i = d - 30;
      v = (i >= 0) ? oppW1[(p * 18 + i) * 32 + o] : 0.f;
    }
  } else if (idx < OFF_PW1) {
    // encB[p][kt][br*2+nt2][lane][j]; br0 rows natural (prop H in regs),
    // br1/br2 rows kperm (ext/opp H pair-packed in Hs)
    const int i2 = idx - OFF_ENCB;
    int t = i2 >> 9;
    const int nt2 = t & 1; t >>= 1;
    const int br = t % 3; t /= 3;
    const int kt = t % 18; const int p = t / 18;
    const int n = kt * 32 + nt2 * 16 + lm;
    if (br == 0)      { const int g = kt >> 1;   v = propW2[((p*9+g)*32 + k_pos)*64 + (n - g*64)]; }
    else if (br == 1) { const int g = (kt >= 9); v = extW2 [((p*2+g)*32 + kperm)*288 + (n - g*288)]; }
    else              {                          v = oppW2 [(p*32 + kperm)*576 + n]; }
  } else if (idx < OFF_PW2) {
    const int i2 = idx - OFF_PW1;
    int t = i2 >> 9;
    const int nt = t & 15; t >>= 4;
    const int kt = t % 18; const int p = t / 18;
    v = piW1[(p * 576 + kt * 32 + kperm) * 256 + nt * 16 + lm];
  } else if (idx < OFF_PW3) {
    const int i2 = idx - OFF_PW2;
    int t = i2 >> 9;
    const int nt = t & 15; t >>= 4;
    const int kt = t & 7; const int p = t >> 3;
    v = piW2[(p * 256 + kt * 32 + kperm) * 256 + nt * 16 + lm];
  } else {
    const int i2 = idx - OFF_PW3;
    int t = i2 >> 9;
    const int kt = t & 7; const int p = t >> 3;
    v = (lm < 3) ? piW3[(p * 256 + kt * 32 + kperm) * 3 + lm] : 0.f;
  }
  ws16[idx] = f2bf(v);
}

// ---------------------------------------------------------------------------
__global__ __launch_bounds__(256, 3) void fused_kernel(
    const float* __restrict__ obs,
    const float* __restrict__ propW1, const float* __restrict__ propB1,
    const float* __restrict__ propB2,
    const float* __restrict__ extB1,  const float* __restrict__ extB2,
    const float* __restrict__ oppB1,  const float* __restrict__ oppB2,
    const unsigned short* __restrict__ wsAll,
    const float* __restrict__ b1v, const float* __restrict__ b2v,
    const float* __restrict__ b3v,
    float* __restrict__ out)
{
  __shared__ __align__(16) unsigned short obs_s[64 * OBS_STRIDE]; //  7168 B
  __shared__ __align__(16) unsigned short Hs[64 * HS_STRIDE];     // 13312 B
  __shared__ __align__(16) unsigned short hbuf[64 * H_STRIDE];    // 33792 B (enc / h1 / h2)

  const unsigned short* b1aW = wsAll + OFF_B1A;
  const unsigned short* encB = wsAll + OFF_ENCB;
  const unsigned short* w1sw = wsAll + OFF_PW1;
  const unsigned short* w2sw = wsAll + OFF_PW2;
  const unsigned short* w3sw = wsAll + OFF_PW3;

  const int tid = threadIdx.x;
  const int p = blockIdx.y, brow = blockIdx.x;
  const int sbase = brow * 64;
  const int wv = tid >> 6, l = tid & 63, lm = l & 15, q = l >> 4;
  const f32x4 zz = {0.f, 0.f, 0.f, 0.f};

  // ---- phase 0: obs -> LDS bf16 ----
  {
    const int s = tid >> 2, c4 = tid & 3;
    if (c4 < 3) {
      const int c0 = c4 * 16;
      const float4* src = (const float4*)&obs[(sbase + s) * 144 + p * 48 + c0];
      float4 v0 = src[0], v1 = src[1], v2 = src[2], v3 = src[3];
      unsigned int pk[8];
      pk[0] = pk2bf(v0.x, v0.y); pk[1] = pk2bf(v0.z, v0.w);
      pk[2] = pk2bf(v1.x, v1.y); pk[3] = pk2bf(v1.z, v1.w);
      pk[4] = pk2bf(v2.x, v2.y); pk[5] = pk2bf(v2.z, v2.w);
      pk[6] = pk2bf(v3.x, v3.y); pk[7] = pk2bf(v3.z, v3.w);
      *(uint4*)&obs_s[s * OBS_STRIDE + c0]     = *(uint4*)&pk[0];
      *(uint4*)&obs_s[s * OBS_STRIDE + c0 + 8] = *(uint4*)&pk[4];
    }
  }
  __syncthreads();

  // ---- phase 1a: ext+opp layer-1 via MFMA (waves 1..3) ----
  if (wv >= 1) {
    const int go = wv - 1;                      // 0: ext0, 1: ext1, 2: opp
    bf16x8 af[4];
    #pragma unroll
    for (int ms = 0; ms < 4; ++ms)
      af[ms] = *(const bf16x8*)&obs_s[(ms * 16 + lm) * OBS_STRIDE + 16 + q * 8];
    bf16x8 bf0 = *(const bf16x8*)&b1aW[((p * 3 + go) * 2 + 0) * 512 + l * 8];
    bf16x8 bf1 = *(const bf16x8*)&b1aW[((p * 3 + go) * 2 + 1) * 512 + l * 8];
    float bias0, bias1;
    if (go < 2) { bias0 = extB1[(p*2+go)*32 + lm]; bias1 = extB1[(p*2+go)*32 + 16 + lm]; }
    else        { bias0 = oppB1[p*32 + lm];        bias1 = oppB1[p*32 + 16 + lm]; }
    #pragma unroll
    for (int ms = 0; ms < 4; ++ms) {
      f32x4 c0 = __builtin_amdgcn_mfma_f32_16x16x32_bf16(af[ms], bf0, zz, 0, 0, 0);
      f32x4 c1 = __builtin_amdgcn_mfma_f32_16x16x32_bf16(af[ms], bf1, zz, 0, 0, 0);
      #pragma unroll
      for (int r = 0; r < 4; ++r) {
        unsigned int w = pk2bf(lrelu(c0[r] + bias0), lrelu(c1[r] + bias1));
        *(unsigned int*)&Hs[(ms * 16 + q * 4 + r) * HS_STRIDE + go * 32 + lm * 2] = w;
      }
    }
  }
  __syncthreads();

  // ---- enc ping-pong groups interleaved with pi-L1 partial accumulation ----
  f32x4 acc[4][4];
  #pragma unroll
  for (int a = 0; a < 4; ++a)
    #pragma unroll
    for (int b = 0; b < 4; ++b) acc[a][b] = zz;

  for (int g = 0; g < 3; ++g) {
    // --- 1b: produce enc group g (k-tiles g*6 .. g*6+5) ---
    int kts[2]; int nkt = 1;
    kts[0] = g * 6 + wv;
    if ((g & 1) == 0 && wv < 2)       { kts[1] = g * 6 + 4 + wv;       nkt = 2; }
    else if ((g & 1) == 1 && wv >= 2) { kts[1] = g * 6 + 4 + (wv - 2); nkt = 2; }

    for (int ik = 0; ik < nkt; ++ik) {
      const int kt = kts[ik], ktloc = kt - g * 6;
      const int gp = kt >> 1, ge = (kt >= 9) ? 1 : 0;
      const int ebase = (p * 18 + kt) * 6;
      bf16x8 wpf[2], wef[2], wof[2];
      float bp[2], be[2], bo[2];
      #pragma unroll
      for (int nt2 = 0; nt2 < 2; ++nt2) {
        wpf[nt2] = *(const bf16x8*)&encB[(ebase + nt2) * 512 + l * 8];
        wef[nt2] = *(const bf16x8*)&encB[(ebase + 2 + nt2) * 512 + l * 8];
        wof[nt2] = *(const bf16x8*)&encB[(ebase + 4 + nt2) * 512 + l * 8];
        const int nc = nt2 * 16 + lm;
        bp[nt2] = propB2[(p * 9 + gp) * 64 + (kt & 1) * 32 + nc];
        be[nt2] = extB2[(p * 2 + ge) * 288 + (kt - ge * 9) * 32 + nc];
        bo[nt2] = oppB2[p * 576 + kt * 32 + nc];
      }
      float w0[8], w1[8], bb[8];
      {
        const float4* p4 = (const float4*)&propW1[(p * 9 + gp) * 64];
        *(float4*)&w0[0] = p4[q * 2];     *(float4*)&w0[4] = p4[q * 2 + 1];
        *(float4*)&w1[0] = p4[8 + q * 2]; *(float4*)&w1[4] = p4[8 + q * 2 + 1];
        const float4* pb4 = (const float4*)&propB1[(p * 9 + gp) * 32];
        *(float4*)&bb[0] = pb4[q * 2];    *(float4*)&bb[4] = pb4[q * 2 + 1];
      }
      #pragma unroll
      for (int ms = 0; ms < 4; ++ms) {
        const int row = ms * 16 + lm;
        // prop layer-1 (K=2) on the fly, natural k order
        const unsigned int xu = *(const unsigned int*)&obs_s[row * OBS_STRIDE + 2 * gp];
        const float x0 = u2f(xu << 16), x1 = u2f(xu & 0xffff0000u);
        unsigned int au[4];
        #pragma unroll
        for (int jj = 0; jj < 4; ++jj) {
          float h0 = lrelu(fmaf(x1, w1[2*jj],   fmaf(x0, w0[2*jj],   bb[2*jj])));
          float h1 = lrelu(fmaf(x1, w1[2*jj+1], fmaf(x0, w0[2*jj+1], bb[2*jj+1])));
          au[jj] = pk2bf(h0, h1);
        }
        bf16x8 apf; __builtin_memcpy(&apf, au, 16);
        bf16x8 ae = *(const bf16x8*)&Hs[row * HS_STRIDE + ge * 32 + q * 8];
        bf16x8 ao = *(const bf16x8*)&Hs[row * HS_STRIDE + 64 + q * 8];
        f32x4 cp[2], ce[2], co[2];
        #pragma unroll
        for (int nt2 = 0; nt2 < 2; ++nt2) {
          cp[nt2] = __builtin_amdgcn_mfma_f32_16x16x32_bf16(apf, wpf[nt2], zz, 0, 0, 0);
          ce[nt2] = __builtin_amdgcn_mfma_f32_16x16x32_bf16(ae,  wef[nt2], zz, 0, 0, 0);
          co[nt2] = __builtin_amdgcn_mfma_f32_16x16x32_bf16(ao,  wof[nt2], zz, 0, 0, 0);
        }
        #pragma unroll
        for (int r = 0; r < 4; ++r) {
          float v0 = lrelu(cp[0][r]+bp[0]) + lrelu(ce[0][r]+be[0]) + lrelu(co[0][r]+bo[0]);
          float v1 = lrelu(cp[1][r]+bp[1]) + lrelu(ce[1][r]+be[1]) + lrelu(co[1][r]+bo[1]);
          *(unsigned int*)&hbuf[(ms * 16 + q * 4 + r) * ENC_STRIDE + ktloc * 32 + lm * 2] =
              pk2bf(v0, v1);
        }
      }
    }
    __syncthreads();

    // --- pi L1 partial over this group's 6 k-tiles ---
    for (int ktloc = 0; ktloc < 6; ++ktloc) {
      const int kt = g * 6 + ktloc;
      bf16x8 afr[4], bfr[4];
      #pragma unroll
      for (int ms = 0; ms < 4; ++ms)
        afr[ms] = *(const bf16x8*)&hbuf[(ms * 16 + lm) * ENC_STRIDE + ktloc * 32 + q * 8];
      const int wb = ((p * 18 + kt) * 16 + wv * 4) * 512 + l * 8;
      #pragma unroll
      for (int nt = 0; nt < 4; ++nt)
        bfr[nt] = *(const bf16x8*)&w1sw[wb + nt * 512];
      #pragma unroll
      for (int ms = 0; ms < 4; ++ms)
        #pragma unroll
        for (int nt = 0; nt < 4; ++nt)
          acc[ms][nt] = __builtin_amdgcn_mfma_f32_16x16x32_bf16(afr[ms], bfr[nt], acc[ms][nt], 0, 0, 0);
    }
    __syncthreads();
  }

  // ---- h1 epilogue (reuses hbuf, stride 264, pair-packed) ----
  {
    float bias_[4];
    #pragma unroll
    for (int nt = 0; nt < 4; ++nt) bias_[nt] = b1v[p * 256 + wv * 64 + nt * 16 + lm];
    #pragma unroll
    for (int ms = 0; ms < 4; ++ms)
      #pragma unroll
      for (int pi2 = 0; pi2 < 2; ++pi2)
        #pragma unroll
        for (int r = 0; r < 4; ++r) {
          float v0 = lrelu(acc[ms][pi2 * 2][r]     + bias_[pi2 * 2]);
          float v1 = lrelu(acc[ms][pi2 * 2 + 1][r] + bias_[pi2 * 2 + 1]);
          *(unsigned int*)&hbuf[(ms * 16 + q * 4 + r) * H_STRIDE + (wv * 2 + pi2) * 32 + lm * 2] =
              pk2bf(v0, v1);
        }
  }
  __syncthreads();

  // ---- pi L2: 256 -> 256 ----
  #pragma unroll
  for (int a = 0; a < 4; ++a)
    #pragma unroll
    for (int b = 0; b < 4; ++b) acc[a][b] = zz;
  for (int kt = 0; kt < 8; ++kt) {
    bf16x8 afr[4], bfr[4];
    #pragma unroll
    for (int ms = 0; ms < 4; ++ms)
      afr[ms] = *(const bf16x8*)&hbuf[(ms * 16 + lm) * H_STRIDE + kt * 32 + q * 8];
    const int wb = ((p * 8 + kt) * 16 + wv * 4) * 512 + l * 8;
    #pragma unroll
    for (int nt = 0; nt < 4; ++nt)
      bfr[nt] = *(const bf16x8*)&w2sw[wb + nt * 512];
    #pragma unroll
    for (int ms = 0; ms < 4; ++ms)
      #pragma unroll
      for (int nt = 0; nt < 4; ++nt)
        acc[ms][nt] = __builtin_amdgcn_mfma_f32_16x16x32_bf16(afr[ms], bfr[nt], acc[ms][nt], 0, 0, 0);
  }
  {
    float bias2[4];
    #pragma unroll
    for (int nt = 0; nt < 4; ++nt) bias2[nt] = b2v[p * 256 + wv * 64 + nt * 16 + lm];
    __syncthreads();                 // all h1 reads complete before overwrite
    #pragma unroll
    for (int ms = 0; ms < 4; ++ms)
      #pragma unroll
      for (int pi2 = 0; pi2 < 2; ++pi2)
        #pragma unroll
        for (int r = 0; r < 4; ++r) {
          float v0 = lrelu(acc[ms][pi2 * 2][r]     + bias2[pi2 * 2]);
          float v1 = lrelu(acc[ms][pi2 * 2 + 1][r] + bias2[pi2 * 2 + 1]);
          *(unsigned int*)&hbuf[(ms * 16 + q * 4 + r) * H_STRIDE + (wv * 2 + pi2) * 32 + lm * 2] =
              pk2bf(v0, v1);
        }
  }
  __syncthreads();

  // ---- pi L3: 256 -> 3 (N padded to 16) + tanh ----
  f32x4 a3 = zz;
  for (int kt = 0; kt < 8; ++kt) {
    bf16x8 afr = *(const bf16x8*)&hbuf[(wv * 16 + lm) * H_STRIDE + kt * 32 + q * 8];
    bf16x8 bfr = *(const bf16x8*)&w3sw[((p * 8 + kt) * 64 + l) * 8];
    a3 = __builtin_amdgcn_mfma_f32_16x16x32_bf16(afr, bfr, a3, 0, 0, 0);
  }
  if (lm < 3) {
    const float bias3 = b3v[p * 3 + lm];
    #pragma unroll
    for (int r = 0; r < 4; ++r) {
      const int s = wv * 16 + q * 4 + r;
      out[(sbase + s) * 9 + p * 3 + lm] = tanhf(a3[r] + bias3);
    }
  }
}

// ---------------------------------------------------------------------------
extern "C" void kernel_launch(void* const* d_in, const int* in_sizes, int n_in,
                              void* d_out, int out_size, void* d_ws, size_t ws_size,
                              hipStream_t stream)
{
  (void)in_sizes; (void)n_in; (void)out_size; (void)ws_size;
  const float* obs    = (const float*)d_in[0];
  const float* propW1 = (const float*)d_in[1];
  const float* propB1 = (const float*)d_in[2];
  const float* propW2 = (const float*)d_in[3];
  const float* propB2 = (const float*)d_in[4];
  const float* extW1  = (const float*)d_in[5];
  const float* extB1  = (const float*)d_in[6];
  const float* extW2  = (const float*)d_in[7];
  const float* extB2  = (const float*)d_in[8];
  const float* oppW1  = (const float*)d_in[9];
  const float* oppB1  = (const float*)d_in[10];
  const float* oppW2  = (const float*)d_in[11];
  const float* oppB2  = (const float*)d_in[12];
  const float* piW1   = (const float*)d_in[13];
  const float* piB1   = (const float*)d_in[14];
  const float* piW2   = (const float*)d_in[15];
  const float* piB2   = (const float*)d_in[16];
  const float* piW3   = (const float*)d_in[17];
  const float* piB3   = (const float*)d_in[18];
  float* out = (float*)d_out;
  unsigned short* ws16 = (unsigned short*)d_ws;

  prep_kernel<<<dim3((WS_TOTAL + 255) / 256), dim3(256), 0, stream>>>(
      propW2, extW1, extW2, oppW1, oppW2, piW1, piW2, piW3, ws16);

  fused_kernel<<<dim3(65536 / 64, 3), dim3(256), 0, stream>>>(
      obs, propW1, propB1, propB2, extB1, extB2, oppB1, oppB2,
      ws16, piB1, piB2, piB3, out);
}